// Round 9
// baseline (212.050 us; speedup 1.0000x reference)
//
#include <hip/hip_runtime.h>
#include <hip/hip_bf16.h>
#include <stdint.h>

namespace {

constexpr int IDIM   = 512;
constexpr int ODIM   = 512;
constexpr int KTOT   = 32768;            // 2 * IDIM * 32
constexpr int BM = 128, BN = 128, BK = 64;
constexpr int SPLITK = 8;
constexpr int KCHUNK = KTOT / SPLITK;    // 4096
constexpr int NSTEP  = KCHUNK / BK;      // 64

typedef short    bf16x8 __attribute__((ext_vector_type(8)));
typedef float    f32x4  __attribute__((ext_vector_type(4)));
typedef uint32_t u32x4  __attribute__((ext_vector_type(4)));

// fast pack: round-half-up (+0x8000) then v_perm_b32 grabs the two high halves.
__device__ __forceinline__ uint32_t pk2f(float lo, float hi) {
  union { float f; uint32_t u; } a, b; a.f = lo; b.f = hi;
  return __builtin_amdgcn_perm(b.u + 0x8000u, a.u + 0x8000u, 0x07060302u);
}

#define WAIT_LGKM0   asm volatile("s_waitcnt lgkmcnt(0)" ::: "memory")
#define WAIT_VM0     asm volatile("s_waitcnt vmcnt(0)" ::: "memory")
#define FENCE        asm volatile("" ::: "memory")

// ---------------- out[b][o] = bias[o]
__global__ __launch_bounds__(256) void init_bias_kernel(const float* __restrict__ bias,
                                                        float* __restrict__ out) {
  int i = blockIdx.x * 256 + threadIdx.x;        // 262144 float4 slots
  ((f32x4*)out)[i] = ((const f32x4*)bias)[i & 127];
}

// ---------------- fused trig-feature GEMM, split-K; W converted in-kernel (no d_ws)
__global__ __launch_bounds__(256, 2) void fkan_gemm_kernel(const float* __restrict__ x,
                                                           const float* __restrict__ fc,
                                                           float* __restrict__ out) {
  __shared__ char lds[65536];   // A dbuf [0,32K); W dbuf [32K,64K)

  const int t    = threadIdx.x;
  const int lane = t & 63;
  const int wave = t >> 6;

  // XCD-aware swizzle (512 % 8 == 0 -> bijective)
  int bid = blockIdx.x;
  int swz = (bid & 7) * 64 + (bid >> 3);
  const int bm = swz & 15;          // 16 M-blocks
  const int bn = (swz >> 4) & 3;    // 4  N-blocks
  const int bz = swz >> 6;          // 8  K-chunks

  const int row0  = bm * BM;
  const int col0  = bn * BN;
  const int kc0   = bz * KCHUNK;          // fc flat row base of this chunk
  const int sflag = bz >> 2;              // 0: cos half, 1: sin half
  const int ibase = (bz & 3) * 128;       // 128 i-values per chunk

  // ---- A generation mapping: thread -> (row gr, i-offset ioff)
  const int gr   = t & 127;
  const int ioff = t >> 7;
  const float* xp = x + (size_t)(row0 + gr) * IDIM + ibase + ioff;
  int awoff[4];                           // swizzled ds_write_b128 offsets
#pragma unroll
  for (int j = 0; j < 4; ++j)
    awoff[j] = gr * 128 + (((ioff * 4 + j) ^ (gr & 7)) << 4);

  // ---- W reg-staging mapping (replaces convert kernel + DMA).
  // Per q: idx = wave*4+q; k-octet ko = idx>>1; o = (idx&1)*64 + lane.
  // Loads fc[kb + ko*8 + j][col0 + o], j=0..7 — each instr = 256B coalesced.
  // LDS slot (byte-identical to verified round-1 layout):
  //   addr = (o>>5)*4096 + ((o>>3)&3)*1024 + ((o&7)*8 + (ko^(o&7)))*16
  int wko[4], wo[4], wldso[4];
#pragma unroll
  for (int q = 0; q < 4; ++q) {
    int idx = wave * 4 + q;
    wko[q] = idx >> 1;
    wo[q]  = (idx & 1) * 64 + lane;
    int o = wo[q];
    wldso[q] = (o >> 5) * 4096 + ((o >> 3) & 3) * 1024 +
               (((o & 7) * 8 + (wko[q] ^ (o & 7))) << 4);
  }

  // ---- fragment read offsets (swizzled) — verified round-1 path
  const int wm = wave >> 1, wn = wave & 1;
  int arow[4], ar7[4], bcol[4], bc7[4];
#pragma unroll
  for (int m = 0; m < 4; ++m) {
    int rr = wm * 64 + m * 16 + (lane & 15);
    arow[m] = rr * 128; ar7[m] = rr & 7;
    int cc = wn * 64 + m * 16 + (lane & 15);
    bcol[m] = cc * 128; bc7[m] = cc & 7;
  }

  f32x4 acc[4][4] = {};
  float r[4][8];                          // staged W f32 (static-indexed after unroll)

  auto stageLoad = [&](int st) {
    const float* base = fc + (size_t)(kc0 + st * BK) * ODIM + col0;
#pragma unroll
    for (int q = 0; q < 4; ++q) {
      const float* s = base + (size_t)(wko[q] * 8) * ODIM + wo[q];
#pragma unroll
      for (int j = 0; j < 8; ++j)
        r[q][j] = s[(size_t)j * ODIM];
    }
  };

  auto stageWrite = [&](int buf) {
#pragma unroll
    for (int q = 0; q < 4; ++q) {
      u32x4 w;
#pragma unroll
      for (int u = 0; u < 4; ++u)
        w[u] = pk2f(r[q][2 * u], r[q][2 * u + 1]);
      *(u32x4*)(lds + 32768 + buf * 16384 + wldso[q]) = w;
    }
  };

  // genA: two independent stride-2 Chebyshev chains (odd/even g) via cos/sin 2x.
  auto genA = [&](int abuf, float ang) {
    float s1, c1;
    __sincosf(ang, &s1, &c1);
    const float c2 = 2.f * c1 * c1 - 1.f;   // cos 2x
    const float s2 = 2.f * s1 * c1;         // sin 2x
    const float k2 = 2.f * c2;
    float po  = sflag ? s1   : c1;          // g = 1
    float pe  = sflag ? s2   : c2;          // g = 2
    float pom = sflag ? -s1  : c1;          // g = -1
    float pem = sflag ? 0.f  : 1.f;         // g = 0
    char* ab = lds + abuf * 16384;
#pragma unroll
    for (int grp = 0; grp < 4; ++grp) {
      u32x4 w;
#pragma unroll
      for (int u = 0; u < 4; ++u) {
        w[u] = pk2f(po, pe);
        float no = k2 * po - pom; pom = po; po = no;
        float ne = k2 * pe - pem; pem = pe; pe = ne;
      }
      *(u32x4*)(ab + awoff[grp]) = w;
    }
  };

  auto compute = [&](int par) {            // verified round-1 fragment path
    const char* ab = lds + par * 16384;
    const char* wb = lds + 32768 + par * 16384;
#pragma unroll
    for (int ks = 0; ks < 2; ++ks) {
      const int ksb = ks * 4 + (lane >> 4);
      bf16x8 af[4], bfr[4];
#pragma unroll
      for (int m = 0; m < 4; ++m)
        af[m] = *(const bf16x8*)(ab + arow[m] + ((ksb ^ ar7[m]) << 4));
#pragma unroll
      for (int n = 0; n < 4; ++n)
        bfr[n] = *(const bf16x8*)(wb + bcol[n] + ((ksb ^ bc7[n]) << 4));
#pragma unroll
      for (int m = 0; m < 4; ++m)
#pragma unroll
        for (int n = 0; n < 4; ++n)
          acc[m][n] = __builtin_amdgcn_mfma_f32_16x16x32_bf16(af[m], bfr[n], acc[m][n], 0, 0, 0);
    }
  };

  // ---- prologue: step 0 into parity-0 buffers
  float angCur  = xp[0];
  float angNext = xp[2];
  stageLoad(0);
  genA(0, angCur);
  WAIT_VM0;                  // r[] and angles landed
  stageWrite(0);
  WAIT_LGKM0;                // A + W ds-writes drained
  __builtin_amdgcn_s_barrier();
  FENCE;

  int par = 0;
  for (int st = 0; st < NSTEP; ++st) {
    if (st + 1 < NSTEP) {
      stageLoad(st + 1);     // 32 coalesced loads issued; land under compute
      float a = angNext;
      int pf = (st + 2 < NSTEP) ? (st + 2) : (NSTEP - 1);
      angNext = xp[2 * pf];
      genA(par ^ 1, a);
    }
    compute(par);
    if (st + 1 < NSTEP) {
      WAIT_VM0;              // own stage loads (issued ~a full compute ago)
      stageWrite(par ^ 1);
      WAIT_LGKM0;            // ds-writes visible to all waves past barrier
      __builtin_amdgcn_s_barrier();
      FENCE;
    }
    par ^= 1;
  }

  // ---- epilogue: split-K reduce via atomics (out pre-initialized with bias)
#pragma unroll
  for (int m = 0; m < 4; ++m) {
#pragma unroll
    for (int n = 0; n < 4; ++n) {
      int rr = row0 + wm * 64 + m * 16 + ((lane >> 4) << 2);
      int cc = col0 + wn * 64 + n * 16 + (lane & 15);
#pragma unroll
      for (int j = 0; j < 4; ++j)
        atomicAdd(out + (size_t)(rr + j) * ODIM + cc, acc[m][n][j]);
    }
  }
}

}  // namespace

extern "C" void kernel_launch(void* const* d_in, const int* in_sizes, int n_in,
                              void* d_out, int out_size, void* d_ws, size_t ws_size,
                              hipStream_t stream) {
  const float* x    = (const float*)d_in[0];
  const float* fc   = (const float*)d_in[1];   // [2,512,32,512] == [32768][512]
  const float* bias = (const float*)d_in[2];
  float*    out = (float*)d_out;
  (void)d_ws; (void)ws_size;

  init_bias_kernel<<<1024, 256, 0, stream>>>(bias, out);
  fkan_gemm_kernel<<<512, 256, 0, stream>>>(x, fc, out);
}